// Round 7
// baseline (508.289 us; speedup 1.0000x reference)
//
#include <hip/hip_runtime.h>
#include <hip/hip_bf16.h>

// MLA prefill: B=1, T=2048, C=2048, H=16, DN=128, DR=64, DV=128, QKD=192,
// RQ=1536, RKV=512. Inputs f32, output f32.
// Round 7: attention rewritten (S^T formulation, per-lane softmax, in-register
// P transpose -- no Ps LDS, no conflicts; paired q-tiles for uniform load,
// 2x MFMA per barrier). GEMMs get a TN=64 tile variant for narrow shapes.

#define T_DIM 2048
#define H_DIM 16
#define SCALE_F 0.07216878364870322f   // 192^-0.5
#define EPS_F 1e-6f
#define NEG_INF (-3.402823466e38f)

typedef __attribute__((ext_vector_type(8))) short short8;
typedef __attribute__((ext_vector_type(4))) float f32x4;
typedef __attribute__((address_space(3))) char lds_char;
typedef const __attribute__((address_space(1))) char glb_char;

__device__ inline void st_out(float* p, float v) { *p = v; }
__device__ inline void st_out(__hip_bfloat16* p, float v) { *p = __float2bfloat16(v); }

__device__ __forceinline__ unsigned pk_bf16(float a, float b) {
    __hip_bfloat16 ha = __float2bfloat16(a), hb = __float2bfloat16(b);
    unsigned short ua, ub;
    __builtin_memcpy(&ua, &ha, 2);
    __builtin_memcpy(&ub, &hb, 2);
    return (unsigned)ua | ((unsigned)ub << 16);
}

// ---------------- f32 -> bf16 cast (optionally zero-padded tail) ------------
__global__ void cast_bf16_kernel(const float* __restrict__ src,
                                 __hip_bfloat16* __restrict__ dst,
                                 int n4_src, int n4_dst) {
    int i = blockIdx.x * 256 + threadIdx.x;
    if (i >= n4_dst) return;
    float4 v = make_float4(0.f, 0.f, 0.f, 0.f);
    if (i < n4_src) v = ((const float4*)src)[i];
    dst[4 * i + 0] = __float2bfloat16(v.x);
    dst[4 * i + 1] = __float2bfloat16(v.y);
    dst[4 * i + 2] = __float2bfloat16(v.z);
    dst[4 * i + 3] = __float2bfloat16(v.w);
}

__global__ void pad_bias_kernel(const float* __restrict__ src, float* __restrict__ dst,
                                int n_src, int n_dst) {
    int i = blockIdx.x * 256 + threadIdx.x;
    if (i < n_dst) dst[i] = (i < n_src) ? src[i] : 0.f;
}

// ---------------- MFMA GEMM: C[M,N] = A[M,K] @ W[N,K]^T + bias[N] -----------
// Tile: 128 x TN (TN in {64,128}). 256 threads / 4 waves.
// TN=128: wave quadrant 64x64 (4x4 mfma tiles). TN=64: wave 64x32 (4x2).
template <int TN, typename OT>
__global__ __launch_bounds__(256) void gemm_mfma_kernel(
    const __hip_bfloat16* __restrict__ A, int lda,
    const __hip_bfloat16* __restrict__ W, int ldw,
    const float* __restrict__ bias,
    OT* __restrict__ C, int ldc, int K) {
    __shared__ __hip_bfloat16 As[128 * 32];
    __shared__ __hip_bfloat16 Bs[TN * 32];
    constexpr int NC = TN / 32;          // mfma col-tiles per wave
    const int tid = threadIdx.x;
    const int w = tid >> 6, lane = tid & 63, qd = lane >> 4, lx = lane & 15;
    const int rowB = blockIdx.y * 128, colB = blockIdx.x * TN;
    const int wr = (w >> 1) * 64, wc = (w & 1) * (TN / 2);

    f32x4 acc[4][NC];
#pragma unroll
    for (int i = 0; i < 4; ++i)
#pragma unroll
        for (int j = 0; j < NC; ++j) acc[i][j] = (f32x4)(0.f);

    for (int k0 = 0; k0 < K; k0 += 32) {
#pragma unroll
        for (int it = 0; it < 2; ++it) {
            const int g = w * 128 + it * 64 + lane;
            const int row = g >> 2, qq = g & 3;
            const __hip_bfloat16* ga = A + (size_t)(rowB + row) * lda + k0 + qq * 8;
            __builtin_amdgcn_global_load_lds((glb_char*)ga,
                                             (lds_char*)((char*)As + (size_t)g * 16), 16, 0, 0);
        }
#pragma unroll
        for (int it = 0; it < TN / 64; ++it) {
            const int g = w * TN + it * 64 + lane;
            const int row = g >> 2, qq = g & 3;
            const __hip_bfloat16* gb = W + (size_t)(colB + row) * ldw + k0 + qq * 8;
            __builtin_amdgcn_global_load_lds((glb_char*)gb,
                                             (lds_char*)((char*)Bs + (size_t)g * 16), 16, 0, 0);
        }
        __syncthreads();

        short8 a[4], b[NC];
#pragma unroll
        for (int rt = 0; rt < 4; ++rt)
            a[rt] = *(const short8*)&As[(wr + rt * 16 + lx) * 32 + qd * 8];
#pragma unroll
        for (int ct = 0; ct < NC; ++ct)
            b[ct] = *(const short8*)&Bs[(wc + ct * 16 + lx) * 32 + qd * 8];
#pragma unroll
        for (int rt = 0; rt < 4; ++rt)
#pragma unroll
            for (int ct = 0; ct < NC; ++ct)
                acc[rt][ct] = __builtin_amdgcn_mfma_f32_16x16x32_bf16(a[rt], b[ct], acc[rt][ct], 0, 0, 0);
        __syncthreads();
    }

#pragma unroll
    for (int rt = 0; rt < 4; ++rt)
#pragma unroll
        for (int j = 0; j < 4; ++j) {
            const int row = rowB + wr + rt * 16 + 4 * qd + j;
#pragma unroll
            for (int ct = 0; ct < NC; ++ct) {
                const int col = colB + wc + ct * 16 + lx;
                st_out(&C[(size_t)row * ldc + col], acc[rt][ct][j] + bias[col]);
            }
        }
}

// ---------------- RMSNorm: f32 in -> bf16 out -------------------------------
__global__ void rmsnorm_kernel(const float* __restrict__ in, __hip_bfloat16* __restrict__ outp,
                               const float* __restrict__ w,
                               int D, int in_stride, int out_stride) {
    const int row = blockIdx.x;
    const float* p = in + (size_t)row * in_stride;
    __hip_bfloat16* o = outp + (size_t)row * out_stride;
    const int tid = threadIdx.x;  // 256
    float ss = 0.f;
    for (int i = tid; i < D; i += 256) { float v = p[i]; ss += v * v; }
    __shared__ float red[256];
    red[tid] = ss;
    __syncthreads();
    for (int off = 128; off > 0; off >>= 1) {
        if (tid < off) red[tid] += red[tid + off];
        __syncthreads();
    }
    const float scale = rsqrtf(red[0] / (float)D + EPS_F);
    for (int i = tid; i < D; i += 256)
        o[i] = __float2bfloat16(p[i] * scale * w[i]);
}

// ---------------- RoPE on q (in-place on bf16 qb: (T, H*192)) ---------------
__global__ void rope_q_bf_kernel(__hip_bfloat16* __restrict__ qb,
                                 const float* __restrict__ freqs) {
    const int idx = blockIdx.x * 256 + threadIdx.x;
    const int t = idx >> 9;
    const int h = (idx >> 5) & 15;
    const int i = idx & 31;
    const float f = freqs[t * 32 + i];
    const float c = cosf(f), s = sinf(f);
    __hip_bfloat16* p = qb + (size_t)t * 3072 + h * 192 + 128 + 2 * i;
    const float xr = __bfloat162float(p[0]), xi = __bfloat162float(p[1]);
    p[0] = __float2bfloat16(xr * c - xi * s);
    p[1] = __float2bfloat16(xr * s + xi * c);
}

// ---------------- RoPE on k_pe: kvpe f32 (T,640) cols[512:576) -> kpe bf16 --
__global__ void rope_k_bf_kernel(const float* __restrict__ kvpe,
                                 const float* __restrict__ freqs,
                                 __hip_bfloat16* __restrict__ kpe) {
    const int idx = blockIdx.x * 256 + threadIdx.x;  // 65536
    const int t = idx >> 5;
    const int i = idx & 31;
    const float f = freqs[t * 32 + i];
    const float c = cosf(f), s = sinf(f);
    const float* src = kvpe + (size_t)t * 640 + 512 + 2 * i;
    const float xr = src[0], xi = src[1];
    kpe[(size_t)t * 64 + 2 * i]     = __float2bfloat16(xr * c - xi * s);
    kpe[(size_t)t * 64 + 2 * i + 1] = __float2bfloat16(xr * s + xi * c);
}

// ---------------- pack V transposed: kvb_bf (T,H*256) -> vT (H,128,T) -------
__global__ void pack_vT_kernel(const __hip_bfloat16* __restrict__ kvb,
                               __hip_bfloat16* __restrict__ vT) {
    const int t0 = blockIdx.x * 64;
    const int h = blockIdx.y;
    const int tid = threadIdx.x;
    __shared__ __hip_bfloat16 Ls[64][136];
#pragma unroll
    for (int it = 0; it < 4; ++it) {
        int c = tid + 256 * it;
        int i = c >> 4, part = c & 15;
        *(uint4*)&Ls[i][part * 8] =
            *(const uint4*)(kvb + (size_t)(t0 + i) * 4096 + h * 256 + 128 + part * 8);
    }
    __syncthreads();
#pragma unroll
    for (int it = 0; it < 32; ++it) {
        int c = tid + 256 * it;
        int d = c >> 6, i = c & 63;
        vT[((size_t)(h * 128 + d)) * 2048 + t0 + i] = Ls[i][d];
    }
}

// ---------------- per-set softmax + PV (inlined; static register indexing) --
__device__ __forceinline__ void softmax_pv(
    f32x4 (&St)[4], f32x4 (&O)[8], float& mv, float& lv,
    const bool diag, const int w, const int lane,
    const __hip_bfloat16* __restrict__ Vsf) {
    const int qd = lane >> 4, lx = lane & 15;
    float sv[4][4];
#pragma unroll
    for (int nt = 0; nt < 4; ++nt)
#pragma unroll
        for (int j = 0; j < 4; ++j) {
            float v = St[nt][j] * SCALE_F;
            if (diag && (16 * nt + 4 * qd + j > 16 * w + lx)) v = NEG_INF;
            sv[nt][j] = v;
        }
    float mt = sv[0][0];
#pragma unroll
    for (int nt = 0; nt < 4; ++nt)
#pragma unroll
        for (int j = 0; j < 4; ++j) mt = fmaxf(mt, sv[nt][j]);
    mt = fmaxf(mt, __shfl_xor(mt, 16, 64));
    mt = fmaxf(mt, __shfl_xor(mt, 32, 64));
    const float mn = fmaxf(mv, mt);
    const float alpha = __expf(mv - mn);
    mv = mn;
    float rs = 0.f;
    float p[4][4];
#pragma unroll
    for (int nt = 0; nt < 4; ++nt)
#pragma unroll
        for (int j = 0; j < 4; ++j) { p[nt][j] = __expf(sv[nt][j] - mn); rs += p[nt][j]; }
    rs += __shfl_xor(rs, 16, 64);
    rs += __shfl_xor(rs, 32, 64);
    lv = lv * alpha + rs;
    // rescale O by per-row alpha (row r = 4*qd+j lives at lane lx=r of my quad)
    float ar[4];
#pragma unroll
    for (int j = 0; j < 4; ++j)
        ar[j] = __shfl(alpha, (lane & 48) + 4 * qd + j, 64);
#pragma unroll
    for (int nt = 0; nt < 8; ++nt)
#pragma unroll
        for (int j = 0; j < 4; ++j) O[nt][j] *= ar[j];
    // pack P (C-layout) and transpose to A-frags in-register
    unsigned u0[4], u1[4];
#pragma unroll
    for (int nt = 0; nt < 4; ++nt) {
        u0[nt] = pk_bf16(p[nt][0], p[nt][1]);
        u1[nt] = pk_bf16(p[nt][2], p[nt][3]);
    }
    const int srcA = ((lane >> 4) & 1) * 32 + lx;
    const int srcB = srcA + 16;
    const bool hiR = (lane & 32) != 0;
#pragma unroll
    for (int kc2 = 0; kc2 < 2; ++kc2) {
        unsigned dw[4];
        {
            unsigned e0 = __shfl((int)u0[2 * kc2], srcA, 64), e1 = __shfl((int)u0[2 * kc2 + 1], srcA, 64);
            dw[0] = hiR ? e1 : e0;
        }
        {
            unsigned e0 = __shfl((int)u1[2 * kc2], srcA, 64), e1 = __shfl((int)u1[2 * kc2 + 1], srcA, 64);
            dw[1] = hiR ? e1 : e0;
        }
        {
            unsigned e0 = __shfl((int)u0[2 * kc2], srcB, 64), e1 = __shfl((int)u0[2 * kc2 + 1], srcB, 64);
            dw[2] = hiR ? e1 : e0;
        }
        {
            unsigned e0 = __shfl((int)u1[2 * kc2], srcB, 64), e1 = __shfl((int)u1[2 * kc2 + 1], srcB, 64);
            dw[3] = hiR ? e1 : e0;
        }
        short8 pa;
        __builtin_memcpy(&pa, dw, 16);
#pragma unroll
        for (int nt = 0; nt < 8; ++nt) {
            short8 vb = *(const short8*)&Vsf[(size_t)(nt * 16 + lx) * 72 + kc2 * 32 + qd * 8];
            O[nt] = __builtin_amdgcn_mfma_f32_16x16x32_bf16(pa, vb, O[nt], 0, 0, 0);
        }
    }
}

__device__ __forceinline__ void attn_epilogue(
    const f32x4 (&O)[8], float lv, int qt, int h, int w, int lane,
    __hip_bfloat16* __restrict__ y) {
    const int qd = lane >> 4, lx = lane & 15;
    const float linv = 1.f / lv;
#pragma unroll
    for (int j = 0; j < 4; ++j) {
        const float lj = __shfl(linv, (lane & 48) + 4 * qd + j, 64);
        const int t = qt * 64 + 16 * w + 4 * qd + j;
        __hip_bfloat16* yr = y + (size_t)t * 2048 + h * 128 + lx;
#pragma unroll
        for (int nt = 0; nt < 8; ++nt) yr[nt * 16] = __float2bfloat16(O[nt][j] * lj);
    }
}

// ---------------- MFMA flash attention, paired q-tiles ----------------------
// Block b handles q-tiles (31-b) and (b); both share each staged K/V tile.
// Uniform 33 MFMA-sets per block; grid (16, H) = 256 blocks.
__global__ __launch_bounds__(256) void attn_mfma_kernel(
    const __hip_bfloat16* __restrict__ q,
    const __hip_bfloat16* __restrict__ kv,
    const __hip_bfloat16* __restrict__ kpe,
    const __hip_bfloat16* __restrict__ vT,
    __hip_bfloat16* __restrict__ y) {
    const int b = blockIdx.x;          // 0..15
    const int h = blockIdx.y;
    const int tid = threadIdx.x;
    const int w = tid >> 6, lane = tid & 63, qd = lane >> 4, lx = lane & 15;
    const int qt0 = 31 - b, qt1 = b;   // HI, LO q-tiles

    __shared__ __hip_bfloat16 Ks[64][200];
    __shared__ __hip_bfloat16 Vs[128][72];

    short8 qf0[6], qf1[6];
    {
        const __hip_bfloat16* qr0 = q + (size_t)(qt0 * 64 + 16 * w + lx) * 3072 + h * 192 + qd * 8;
        const __hip_bfloat16* qr1 = q + (size_t)(qt1 * 64 + 16 * w + lx) * 3072 + h * 192 + qd * 8;
#pragma unroll
        for (int kc = 0; kc < 6; ++kc) {
            qf0[kc] = *(const short8*)(qr0 + kc * 32);
            qf1[kc] = *(const short8*)(qr1 + kc * 32);
        }
    }

    f32x4 O0[8], O1[8];
#pragma unroll
    for (int i = 0; i < 8; ++i) { O0[i] = (f32x4)(0.f); O1[i] = (f32x4)(0.f); }
    float m0 = NEG_INF, l0 = 0.f, m1 = NEG_INF, l1 = 0.f;

    const int nIt = 32 - b;            // tiles 0..31-b (HI range)
    for (int it = 0; it < nIt; ++it) {
        const int s0 = it * 64;
        __syncthreads();
        // stage K-tile (nope from kv, pe from kpe) and V-tile (from vT)
#pragma unroll
        for (int c0 = 0; c0 < 4; ++c0) {
            int c = tid + 256 * c0;
            int key = c >> 4, part = c & 15;
            *(uint4*)&Ks[key][part * 8] =
                *(const uint4*)(kv + (size_t)(s0 + key) * 4096 + h * 256 + part * 8);
        }
#pragma unroll
        for (int c0 = 0; c0 < 2; ++c0) {
            int c = tid + 256 * c0;
            int key = c >> 3, part = c & 7;
            *(uint4*)&Ks[key][128 + part * 8] =
                *(const uint4*)(kpe + (size_t)(s0 + key) * 64 + part * 8);
        }
#pragma unroll
        for (int c0 = 0; c0 < 4; ++c0) {
            int c = tid + 256 * c0;
            int dv = c >> 3, part = c & 7;
            *(uint4*)&Vs[dv][part * 8] =
                *(const uint4*)(vT + ((size_t)(h * 128 + dv)) * 2048 + s0 + part * 8);
        }
        __syncthreads();

        const bool doLO = (it <= b);

        // S^T = K Q^T  (A = K rows -> keys, B = Q rows; shared K frags)
        f32x4 St0[4], St1[4];
#pragma unroll
        for (int nt = 0; nt < 4; ++nt) { St0[nt] = (f32x4)(0.f); St1[nt] = (f32x4)(0.f); }
#pragma unroll
        for (int kc = 0; kc < 6; ++kc)
#pragma unroll
            for (int nt = 0; nt < 4; ++nt) {
                short8 ka = *(const short8*)&Ks[nt * 16 + lx][kc * 32 + qd * 8];
                St0[nt] = __builtin_amdgcn_mfma_f32_16x16x32_bf16(ka, qf0[kc], St0[nt], 0, 0, 0);
                if (doLO)
                    St1[nt] = __builtin_amdgcn_mfma_f32_16x16x32_bf16(ka, qf1[kc], St1[nt], 0, 0, 0);
            }

        softmax_pv(St0, O0, m0, l0, it == qt0, w, lane, &Vs[0][0]);
        if (doLO)
            softmax_pv(St1, O1, m1, l1, it == qt1, w, lane, &Vs[0][0]);
    }

    attn_epilogue(O0, l0, qt0, h, w, lane, y);
    attn_epilogue(O1, l1, qt1, h, w, lane, y);
}

extern "C" void kernel_launch(void* const* d_in, const int* in_sizes, int n_in,
                              void* d_out, int out_size, void* d_ws, size_t ws_size,
                              hipStream_t stream) {
    const float* x         = (const float*)d_in[0];
    const float* freqs     = (const float*)d_in[1];
    const float* wq_a      = (const float*)d_in[2];
    const float* bq_a      = (const float*)d_in[3];
    const float* q_norm_w  = (const float*)d_in[4];
    const float* wq_b      = (const float*)d_in[5];
    const float* bq_b      = (const float*)d_in[6];
    const float* wkv_a     = (const float*)d_in[7];
    const float* bkv_a     = (const float*)d_in[8];
    const float* kv_norm_w = (const float*)d_in[9];
    const float* wkv_b     = (const float*)d_in[10];
    const float* bkv_b     = (const float*)d_in[11];
    const float* wo        = (const float*)d_in[12];
    const float* bo        = (const float*)d_in[13];
    float* out = (float*)d_out;

    // Workspace layout, ~76.3 MB total.
    char* p = (char*)d_ws;
    float* q_lat = (float*)p;                        p += (size_t)2048 * 1536 * 4;  // later hosts yb_bf
    float* kvpe  = (float*)p;                        p += (size_t)2048 * 640 * 4;
    __hip_bfloat16* x_bf      = (__hip_bfloat16*)p;  p += (size_t)2048 * 2048 * 2;  // later hosts vT
    __hip_bfloat16* q_lat_bf  = (__hip_bfloat16*)p;  p += (size_t)2048 * 1536 * 2;
    __hip_bfloat16* qb_bf     = (__hip_bfloat16*)p;  p += (size_t)2048 * 3072 * 2;
    __hip_bfloat16* kv_lat_bf = (__hip_bfloat16*)p;  p += (size_t)2048 * 512 * 2;
    __hip_bfloat16* kvb_bf    = (__hip_bfloat16*)p;  p += (size_t)2048 * 4096 * 2;
    __hip_bfloat16* kpe_bf    = (__hip_bfloat16*)p;  p += (size_t)2048 * 64 * 2;
    __hip_bfloat16* WA        = (__hip_bfloat16*)p;  p += (size_t)3072 * 1536 * 2;  // weight arena
    __hip_bfloat16* WB        = (__hip_bfloat16*)p;  p += (size_t)640 * 2048 * 2;   // padded wkv_a
    float* bkv_pad = (float*)p;                      p += (size_t)640 * 4;
    __hip_bfloat16* vT    = x_bf;                    // alias: x_bf dead after GEMM 2
    __hip_bfloat16* yb_bf = (__hip_bfloat16*)q_lat;  // alias: q_lat dead after rmsnorm

    // ---- casts & pads ----
    cast_bf16_kernel<<<4096, 256, 0, stream>>>(x, x_bf, 1048576, 1048576);
    cast_bf16_kernel<<<3072, 256, 0, stream>>>(wq_a, WA, 786432, 786432);
    // GEMM 1: q_lat = x @ wq_a^T + bq_a  (f32 out)
    gemm_mfma_kernel<64, float><<<dim3(24, 16), 256, 0, stream>>>(x_bf, 2048, WA, 2048, bq_a, q_lat, 1536, 2048);
    cast_bf16_kernel<<<1280, 256, 0, stream>>>(wkv_a, WB, 294912, 327680);
    pad_bias_kernel<<<3, 256, 0, stream>>>(bkv_a, bkv_pad, 576, 640);
    // GEMM 2: kvpe = x @ wkv_a^T + bkv_a  (f32 out, N padded to 640)
    gemm_mfma_kernel<64, float><<<dim3(10, 16), 256, 0, stream>>>(x_bf, 2048, WB, 2048, bkv_pad, kvpe, 640, 2048);
    // rmsnorm q -> bf16
    rmsnorm_kernel<<<2048, 256, 0, stream>>>(q_lat, q_lat_bf, q_norm_w, 1536, 1536, 1536);
    cast_bf16_kernel<<<4608, 256, 0, stream>>>(wq_b, WA, 1179648, 1179648);
    // GEMM 3: qb_bf = q_lat_bf @ wq_b^T + bq_b
    gemm_mfma_kernel<64, __hip_bfloat16><<<dim3(48, 16), 256, 0, stream>>>(q_lat_bf, 1536, WA, 1536, bq_b, qb_bf, 3072, 1536);
    rope_q_bf_kernel<<<4096, 256, 0, stream>>>(qb_bf, freqs);
    rope_k_bf_kernel<<<256, 256, 0, stream>>>(kvpe, freqs, kpe_bf);
    rmsnorm_kernel<<<2048, 256, 0, stream>>>(kvpe, kv_lat_bf, kv_norm_w, 512, 640, 512);
    cast_bf16_kernel<<<2048, 256, 0, stream>>>(wkv_b, WA, 524288, 524288);
    // GEMM 4: kvb_bf = kv_lat_bf @ wkv_b^T + bkv_b  (wide N, keep TN=128)
    gemm_mfma_kernel<128, __hip_bfloat16><<<dim3(32, 16), 256, 0, stream>>>(kv_lat_bf, 512, WA, 512, bkv_b, kvb_bf, 4096, 512);
    pack_vT_kernel<<<dim3(32, 16), 256, 0, stream>>>(kvb_bf, vT);
    // MFMA flash attention -> yb_bf (paired q-tiles, 256 blocks)
    attn_mfma_kernel<<<dim3(16, 16), 256, 0, stream>>>(qb_bf, kvb_bf, kpe_bf, vT, yb_bf);
    cast_bf16_kernel<<<4096, 256, 0, stream>>>(wo, WA, 1048576, 1048576);
    // GEMM 5: out = yb_bf @ wo^T + bo  (f32 out)
    gemm_mfma_kernel<64, float><<<dim3(32, 16), 256, 0, stream>>>(yb_bf, 2048, WA, 2048, bo, out, 2048, 2048);
}